// Round 6
// baseline (4377.349 us; speedup 1.0000x reference)
//
#include <hip/hip_runtime.h>
#include <hip/hip_fp16.h>
#include <math.h>

#define N_NODES 50000
#define E_EDGES 800000
#define E_TOT   850000   // E + N self loops
#define HC 128
#define NHEAD 4
#define LIN 256
#define OUTC 10
#define NG 64
#define NEG_SLOPE 0.2f

// (dst, src-tile)-sorted CSR (R16, kept): edges of each node contiguous,
// tile-ordered. R17: persistent co-resident aggr + soft barriers align all
// waves on the same tile IN TIME (R16 showed hit-rate ~1/NT from drift).
#define NT 5
#define TILE_N 10000
#define NSEG (N_NODES * NT)     // 250000 (dst,tile) cells
#define SCAN_BLOCKS 245         // 245 * 1024 cells >= NSEG
#define NBLK 1024               // aggr grid: 4 blocks/CU x 256 CU, co-resident
#define NWAVE (NBLK * 4)        // 4096 waves
#define NPW 13                  // consecutive nodes per wave: 4096*13 >= 50000

__device__ __forceinline__ float lrelu(float v) { return v > 0.f ? v : NEG_SLOPE * v; }

typedef _Float16 half8v __attribute__((ext_vector_type(8)));
typedef float    float4v __attribute__((ext_vector_type(4)));

// ---------------------------------------------------------------------------
// MFMA GEMM + attention logits (unchanged from the 551us baseline).
// ---------------------------------------------------------------------------
__global__ __launch_bounds__(256) void k_gemm_mfma(
    const float* __restrict__ x, const float* __restrict__ W,
    const float* __restrict__ a_s, const float* __restrict__ a_d,
    __half* __restrict__ h, float* __restrict__ asrc, float* __restrict__ adst) {
  __shared__ _Float16 Wt[128 * 136];       // W^T fp16, padded row stride 136
  __shared__ _Float16 hst[4][16][136];     // per-wave C staging (padded)
  __shared__ float aS[HC], aD[HC];
  int tid = threadIdx.x;
  if (tid < HC) { aS[tid] = a_s[tid]; aD[tid] = a_d[tid]; }
  for (int i = 0; i < 64; i++) {
    int idx = tid + i * 256;               // 16384 elements
    int k = idx >> 7, n = idx & 127;
    Wt[n * 136 + k] = (_Float16)W[idx];
  }
  __syncthreads();

  int wv = tid >> 6, lane = tid & 63;
  int quad = lane >> 4, low = lane & 15;
  int rowbase = blockIdx.x * 64 + wv * 16;
  int row = rowbase + low;
  int rowc = row < N_NODES ? row : N_NODES - 1;  // clamp; stores guarded

  float4v acc[8];
#pragma unroll
  for (int t = 0; t < 8; t++) acc[t] = (float4v){0.f, 0.f, 0.f, 0.f};

#pragma unroll
  for (int k4 = 0; k4 < 4; k4++) {
    int kb = k4 * 32 + quad * 8;
    float4 xa = *(const float4*)(x + (size_t)rowc * HC + kb);
    float4 xb = *(const float4*)(x + (size_t)rowc * HC + kb + 4);
    half8v af;
    af[0] = (_Float16)xa.x; af[1] = (_Float16)xa.y;
    af[2] = (_Float16)xa.z; af[3] = (_Float16)xa.w;
    af[4] = (_Float16)xb.x; af[5] = (_Float16)xb.y;
    af[6] = (_Float16)xb.z; af[7] = (_Float16)xb.w;
    half8v bf[8];
#pragma unroll
    for (int t = 0; t < 8; t++)
      bf[t] = *(const half8v*)&Wt[(t * 16 + low) * 136 + kb];
#pragma unroll
    for (int t = 0; t < 8; t++)
      acc[t] = __builtin_amdgcn_mfma_f32_16x16x32_f16(af, bf[t], acc[t], 0, 0, 0);
  }

#pragma unroll
  for (int t = 0; t < 8; t++)
#pragma unroll
    for (int r = 0; r < 4; r++)
      hst[wv][quad * 4 + r][t * 16 + low] = (_Float16)acc[t][r];
  __syncthreads();

  {
    int r = lane >> 2, part = lane & 3;
    int grow = rowbase + r;
    if (grow < N_NODES) {
      const float4* src = (const float4*)&hst[wv][r][part * 32];
      float4* dst = (float4*)(h + (size_t)grow * HC + part * 32);
#pragma unroll
      for (int i = 0; i < 4; i++) dst[i] = src[i];
    }
  }
  {
    int grow = rowbase + low;
    float ss = 0.f, dd = 0.f;
#pragma unroll
    for (int i = 0; i < 32; i++) {
      float hv = (float)hst[wv][low][quad * 32 + i];
      ss += hv * aS[quad * 32 + i];
      dd += hv * aD[quad * 32 + i];
    }
    if (grow < N_NODES) {
      asrc[grow * NHEAD + quad] = ss;
      adst[grow * NHEAD + quad] = dd;
    }
  }
}

// ---------------------------------------------------------------------------
// CSR build, counting-sorted by (dst, src_tile). Hierarchical scan (R16).
// ---------------------------------------------------------------------------
__global__ __launch_bounds__(256) void k_hist(
    const int* __restrict__ dst, const int* __restrict__ src,
    int* __restrict__ degT) {
  int e = blockIdx.x * 256 + threadIdx.x;
  if (e >= E_TOT) return;
  int d, s;
  if (e < E_EDGES) { d = dst[e]; s = src[e]; } else { d = s = e - E_EDGES; }
  int t = s / TILE_N;
  atomicAdd(&degT[d * NT + t], 1);
}

__global__ __launch_bounds__(256) void k_scanA(
    const int* __restrict__ degT, int* __restrict__ bsum) {
  __shared__ int ps[256];
  int tid = threadIdx.x, b = blockIdx.x;
  int base = b * 1024 + tid * 4;
  int s = 0;
#pragma unroll
  for (int i = 0; i < 4; i++) {
    int idx = base + i;
    if (idx < NSEG) s += degT[idx];
  }
  ps[tid] = s;
  __syncthreads();
  for (int off = 128; off > 0; off >>= 1) {
    if (tid < off) ps[tid] += ps[tid + off];
    __syncthreads();
  }
  if (tid == 0) bsum[b] = ps[0];
}

// scanB: exclusive scan of block sums (+ pooled zero + barrier-counter zero)
__global__ __launch_bounds__(256) void k_scanB(
    const int* __restrict__ bsum, int* __restrict__ boff,
    unsigned* __restrict__ pooled, int* __restrict__ pc) {
  __shared__ int ps[256];
  int tid = threadIdx.x;
  {
    uint4* p4 = (uint4*)pooled;
#pragma unroll
    for (int i = 0; i < 8; i++) p4[tid * 8 + i] = make_uint4(0u, 0u, 0u, 0u);
  }
  if (tid < 24) pc[tid] = 0;   // 3 layers x 8 soft-barrier counters
  int s = (tid < SCAN_BLOCKS) ? bsum[tid] : 0;
  ps[tid] = s;
  __syncthreads();
  for (int off = 1; off < 256; off <<= 1) {
    int v = (tid >= off) ? ps[tid - off] : 0;
    __syncthreads();
    ps[tid] += v;
    __syncthreads();
  }
  if (tid < SCAN_BLOCKS) boff[tid] = ps[tid] - s;  // exclusive
}

__global__ __launch_bounds__(256) void k_scanC(
    const int* __restrict__ degT, const int* __restrict__ boff,
    int* __restrict__ offT) {
  __shared__ int ps[256];
  int tid = threadIdx.x, b = blockIdx.x;
  int base = b * 1024 + tid * 4;
  int d[4];
  int s = 0;
#pragma unroll
  for (int i = 0; i < 4; i++) {
    int idx = base + i;
    d[i] = (idx < NSEG) ? degT[idx] : 0;
    s += d[i];
  }
  ps[tid] = s;
  __syncthreads();
  for (int off = 1; off < 256; off <<= 1) {
    int v = (tid >= off) ? ps[tid - off] : 0;
    __syncthreads();
    ps[tid] += v;
    __syncthreads();
  }
  int run = boff[b] + ps[tid] - s;
#pragma unroll
  for (int i = 0; i < 4; i++) {
    int idx = base + i;
    if (idx < NSEG) {
      offT[idx] = run;
      run += d[i];
      if (idx == NSEG - 1) offT[NSEG] = run;
    }
  }
}

__global__ __launch_bounds__(256) void k_scatter(
    const int* __restrict__ src, const int* __restrict__ dst,
    const int* __restrict__ offT, int* __restrict__ cntT,
    int* __restrict__ csr_src) {
  int e = blockIdx.x * 256 + threadIdx.x;
  if (e >= E_TOT) return;
  int s, d;
  if (e < E_EDGES) { s = src[e]; d = dst[e]; } else { s = d = e - E_EDGES; }
  int t = s / TILE_N;
  int pos = offT[d * NT + t] + atomicAdd(&cntT[d * NT + t], 1);
  csr_src[pos] = s;
}

#define BFLY_MAX4(m0, m1, m2, m3)                         \
  _Pragma("unroll") for (int off = 1; off < 64; off <<= 1) { \
    m0 = fmaxf(m0, __shfl_xor(m0, off));                  \
    m1 = fmaxf(m1, __shfl_xor(m1, off));                  \
    m2 = fmaxf(m2, __shfl_xor(m2, off));                  \
    m3 = fmaxf(m3, __shfl_xor(m3, off));                  \
  }
#define BFLY_SUM4(s0, s1, s2, s3)                         \
  _Pragma("unroll") for (int off = 1; off < 64; off <<= 1) { \
    s0 += __shfl_xor(s0, off);                            \
    s1 += __shfl_xor(s1, off);                            \
    s2 += __shfl_xor(s2, off);                            \
    s3 += __shfl_xor(s3, off);                            \
  }

// ---------------------------------------------------------------------------
// R17: persistent co-resident aggregation with TIME-ALIGNED tile phases.
// 1024 blocks (4/CU via launch_bounds cap), wave owns 13 consecutive nodes.
// Phase 0: per-node softmax stats (m, 1/S, adh) -> per-wave LDS.
// Tile phase t: per node, sweep its (dst,t) segment: scalar sv -> broadcast
// asrc read -> recompute w -> ONE 256B h-row gather per edge (LAW R5/R7/R10).
// Accumulate in regs, one LDS RMW per (node,tile). Accumulators in LDS, NOT
// register arrays (R15's VGPR=44 showed k-indexed arrays spill to scratch).
// Soft barrier between phases: bounded atomic spin, disable-on-timeout ->
// pure locality throttle, no correctness dependence, degrades to R16.
// ---------------------------------------------------------------------------
__global__ __launch_bounds__(256, 4) void k_aggr(
    const int* __restrict__ offT, const int* __restrict__ csr_src,
    const float* __restrict__ asrc, const float* __restrict__ adst,
    const __half* __restrict__ h, const float* __restrict__ bias,
    const int* __restrict__ batch, float* __restrict__ out_h,
    unsigned* __restrict__ pooled, int* __restrict__ pc, int do_pool) {
  __shared__ float axy[4][NPW][64][2];      // 26.6 KB accumulators
  __shared__ float mst[4][NPW][NHEAD][3];   // m, 1/S, adh
  __shared__ int ok_s;
  int tid = threadIdx.x, wl = tid >> 6, lane = tid & 63;
  int wid = blockIdx.x * 4 + wl;
  int nodebase = wid * NPW;
  int hc = lane >> 4;

  // ---- phase 0: softmax stats (asrc/csr traffic only, no h) ----
  for (int k = 0; k < NPW; k++) {
    int node = nodebase + k;
    if (node >= N_NODES) break;
    axy[wl][k][lane][0] = 0.f;
    axy[wl][k][lane][1] = 0.f;
    int lo = offT[node * NT], hi = offT[node * NT + NT];
    int deg = hi - lo;
    float4 ad4 = ((const float4*)adst)[node];
    float m0, m1, m2, m3, s0, s1, s2, s3;
    if (deg <= 64) {
      int j = lo + lane;
      bool valid = j < hi;
      int sv = valid ? csr_src[j] : 0;
      float4 a4 = ((const float4*)asrc)[sv];
      float e0 = valid ? lrelu(a4.x + ad4.x) : -1e30f;
      float e1 = valid ? lrelu(a4.y + ad4.y) : -1e30f;
      float e2 = valid ? lrelu(a4.z + ad4.z) : -1e30f;
      float e3 = valid ? lrelu(a4.w + ad4.w) : -1e30f;
      m0 = e0; m1 = e1; m2 = e2; m3 = e3;
      BFLY_MAX4(m0, m1, m2, m3)
      float w0 = expf(e0 - m0), w1 = expf(e1 - m1);
      float w2 = expf(e2 - m2), w3 = expf(e3 - m3);
      s0 = w0; s1 = w1; s2 = w2; s3 = w3;
      BFLY_SUM4(s0, s1, s2, s3)
    } else {
      float M0 = -1e30f, M1 = -1e30f, M2 = -1e30f, M3 = -1e30f;
      for (int c = lo; c < hi; c += 64) {
        int j = c + lane;
        bool valid = j < hi;
        int sv = valid ? csr_src[j] : 0;
        float4 a4 = ((const float4*)asrc)[sv];
        float e0 = valid ? lrelu(a4.x + ad4.x) : -1e30f;
        float e1 = valid ? lrelu(a4.y + ad4.y) : -1e30f;
        float e2 = valid ? lrelu(a4.z + ad4.z) : -1e30f;
        float e3 = valid ? lrelu(a4.w + ad4.w) : -1e30f;
        BFLY_MAX4(e0, e1, e2, e3)
        M0 = fmaxf(M0, e0); M1 = fmaxf(M1, e1);
        M2 = fmaxf(M2, e2); M3 = fmaxf(M3, e3);
      }
      float S0 = 0.f, S1 = 0.f, S2 = 0.f, S3 = 0.f;
      for (int c = lo; c < hi; c += 64) {
        int j = c + lane;
        bool valid = j < hi;
        int sv = valid ? csr_src[j] : 0;
        float4 a4 = ((const float4*)asrc)[sv];
        float e0 = valid ? lrelu(a4.x + ad4.x) : -1e30f;
        float e1 = valid ? lrelu(a4.y + ad4.y) : -1e30f;
        float e2 = valid ? lrelu(a4.z + ad4.z) : -1e30f;
        float e3 = valid ? lrelu(a4.w + ad4.w) : -1e30f;
        float w0 = expf(e0 - M0), w1 = expf(e1 - M1);
        float w2 = expf(e2 - M2), w3 = expf(e3 - M3);
        float t0 = w0, t1 = w1, t2 = w2, t3 = w3;
        BFLY_SUM4(t0, t1, t2, t3)
        S0 += t0; S1 += t1; S2 += t2; S3 += t3;
      }
      m0 = M0; m1 = M1; m2 = M2; m3 = M3;
      s0 = S0; s1 = S1; s2 = S2; s3 = S3;
    }
    if (lane < 4) {
      float mm = lane == 0 ? m0 : lane == 1 ? m1 : lane == 2 ? m2 : m3;
      float ss = lane == 0 ? s0 : lane == 1 ? s1 : lane == 2 ? s2 : s3;
      float ad = lane == 0 ? ad4.x : lane == 1 ? ad4.y : lane == 2 ? ad4.z : ad4.w;
      mst[wl][k][lane][0] = mm;
      mst[wl][k][lane][1] = 1.f / ss;
      mst[wl][k][lane][2] = ad;
    }
  }

  // soft barrier: arrive always; wait bounded; disable after first timeout
  bool coh = true;
  int expect = gridDim.x;
#define SOFT_BAR(idx)                                                        \
  {                                                                          \
    __syncthreads();                                                         \
    if (tid == 0) {                                                          \
      __hip_atomic_fetch_add(&pc[idx], 1, __ATOMIC_ACQ_REL,                  \
                             __HIP_MEMORY_SCOPE_AGENT);                      \
      int ok = 1;                                                            \
      if (coh) {                                                             \
        int it = 0;                                                          \
        while (__hip_atomic_load(&pc[idx], __ATOMIC_ACQUIRE,                 \
                                 __HIP_MEMORY_SCOPE_AGENT) < expect) {       \
          if (++it > 1500) { ok = 0; break; }                                \
          __builtin_amdgcn_s_sleep(2);                                       \
        }                                                                    \
      } else ok = 0;                                                         \
      ok_s = ok;                                                             \
    }                                                                        \
    __syncthreads();                                                         \
    coh = coh && (ok_s != 0);                                                \
  }

  SOFT_BAR(0)

  // ---- tile phases: time-aligned L2-resident gathers ----
  for (int t = 0; t < NT; t++) {
    for (int k = 0; k < NPW; k++) {
      int node = nodebase + k;
      if (node >= N_NODES) break;
      int e0 = offT[node * NT + t], e1 = offT[node * NT + t + 1];
      if (e0 == e1) continue;
      float mk = mst[wl][k][hc][0];
      float adh = mst[wl][k][hc][2];
      float axk = 0.f, ayk = 0.f;
      int j = e0;
      for (; j + 2 <= e1; j += 2) {
        int sa = csr_src[j], sb = csr_src[j + 1];
        float Aa = asrc[(size_t)sa * NHEAD + hc];
        float Ab = asrc[(size_t)sb * NHEAD + hc];
        float2 Ha = __half22float2(*(const __half2*)(h + (size_t)sa * HC + lane * 2));
        float2 Hb = __half22float2(*(const __half2*)(h + (size_t)sb * HC + lane * 2));
        float wa = expf(lrelu(Aa + adh) - mk);
        float wb = expf(lrelu(Ab + adh) - mk);
        axk += wa * Ha.x + wb * Hb.x;
        ayk += wa * Ha.y + wb * Hb.y;
      }
      if (j < e1) {
        int sa = csr_src[j];
        float Aa = asrc[(size_t)sa * NHEAD + hc];
        float2 Ha = __half22float2(*(const __half2*)(h + (size_t)sa * HC + lane * 2));
        float wa = expf(lrelu(Aa + adh) - mk);
        axk += wa * Ha.x;
        ayk += wa * Ha.y;
      }
      axy[wl][k][lane][0] += axk;
      axy[wl][k][lane][1] += ayk;
    }
    if (t < NT - 1) SOFT_BAR(1 + t)
  }

  // ---- epilogue: normalize, bias, relu, store (+pool) ----
  float2 b = *(const float2*)(bias + lane * 2);
  for (int k = 0; k < NPW; k++) {
    int node = nodebase + k;
    if (node >= N_NODES) break;
    float rd = mst[wl][k][hc][1];
    float vx = fmaxf(axy[wl][k][lane][0] * rd + b.x, 0.f);
    float vy = fmaxf(axy[wl][k][lane][1] * rd + b.y, 0.f);
    *(float2*)(out_h + (size_t)node * HC + lane * 2) = make_float2(vx, vy);
    if (do_pool) {
      int g = batch[node];
      unsigned* pp = pooled + g * HC + lane * 2;
      // post-relu values >= 0: bit compare == float compare; init 0 matches
      // the reference's where(isfinite, pooled, 0) empty-graph guard.
      atomicMax(pp + 0, __float_as_uint(vx));
      atomicMax(pp + 1, __float_as_uint(vy));
    }
  }
#undef SOFT_BAR
}

// final head: out[g] = (pooled[g] @ Wlin + blin) @ Wout + bout ; 1 block/graph
__global__ __launch_bounds__(256) void k_mlp(
    const float* __restrict__ pooled, const float* __restrict__ Wlin,
    const float* __restrict__ blin, const float* __restrict__ Wout,
    const float* __restrict__ bout, float* __restrict__ out) {
  __shared__ float p[HC];
  __shared__ float z[LIN];
  int g = blockIdx.x, tid = threadIdx.x;
  if (tid < HC) p[tid] = pooled[g * HC + tid];
  __syncthreads();
  float zv = blin[tid];
  for (int k = 0; k < HC; k++) zv += p[k] * Wlin[k * LIN + tid];
  z[tid] = zv;
  __syncthreads();
  if (tid < OUTC) {
    float o = bout[tid];
    for (int k = 0; k < LIN; k++) o += z[k] * Wout[k * OUTC + tid];
    out[g * OUTC + tid] = o;
  }
}

extern "C" void kernel_launch(void* const* d_in, const int* in_sizes, int n_in,
                              void* d_out, int out_size, void* d_ws, size_t ws_size,
                              hipStream_t stream) {
  const float* x     = (const float*)d_in[0];
  const int*   ei    = (const int*)d_in[1];
  const int*   batch = (const int*)d_in[2];
  const float* Wl[3] = {(const float*)d_in[3], (const float*)d_in[7], (const float*)d_in[11]};
  const float* As[3] = {(const float*)d_in[4], (const float*)d_in[8], (const float*)d_in[12]};
  const float* Ad[3] = {(const float*)d_in[5], (const float*)d_in[9], (const float*)d_in[13]};
  const float* Bi[3] = {(const float*)d_in[6], (const float*)d_in[10], (const float*)d_in[14]};
  const float* Wlin  = (const float*)d_in[15];
  const float* blin  = (const float*)d_in[16];
  const float* Wout  = (const float*)d_in[17];
  const float* bout  = (const float*)d_in[18];
  float* out = (float*)d_out;

  // workspace layout (float offsets)
  float* ws = (float*)d_ws;
  __half*   h       = (__half*)ws;                 // N*128 halves (3.2M fl)
  float*    nodeB   = ws + 3200000;                // N*128 fp32   (6.4M fl)
  float*    asrc    = ws + 9600000;                // N*4
  float*    adst    = ws + 9800000;                // N*4
  int*      degT    = (int*)(ws + 10000000);       // 250k (adjacent to cntT)
  int*      cntT    = (int*)(ws + 10250000);       // 250k
  int*      offT    = (int*)(ws + 10500000);       // 250001
  int*      csr_src = (int*)(ws + 10750004);       // E_TOT (+pad)
  unsigned* pooled  = (unsigned*)(ws + 11600008);  // 64*128
  int*      bsum    = (int*)(ws + 11608200);       // 245
  int*      boff    = (int*)(ws + 11608456);       // 245
  int*      pc      = (int*)(ws + 11608704);       // 24 barrier counters

  const int* srcp = ei;
  const int* dstp = ei + E_EDGES;

  hipMemsetAsync(degT, 0, 2 * NSEG * sizeof(int), stream);  // degT + cntT

  // (dst, src_tile)-sorted CSR — built once, reused by all 3 layers
  k_hist<<<(E_TOT + 255) / 256, 256, 0, stream>>>(dstp, srcp, degT);
  k_scanA<<<SCAN_BLOCKS, 256, 0, stream>>>(degT, bsum);
  k_scanB<<<1, 256, 0, stream>>>(bsum, boff, pooled, pc);
  k_scanC<<<SCAN_BLOCKS, 256, 0, stream>>>(degT, boff, offT);
  k_scatter<<<(E_TOT + 255) / 256, 256, 0, stream>>>(srcp, dstp, offT, cntT, csr_src);

  const float* lin_in = x;
  for (int L = 0; L < 3; L++) {
    k_gemm_mfma<<<(N_NODES + 63) / 64, 256, 0, stream>>>(
        lin_in, Wl[L], As[L], Ad[L], h, asrc, adst);
    k_aggr<<<NBLK, 256, 0, stream>>>(
        offT, csr_src, asrc, adst, h, Bi[L], batch,
        nodeB, pooled, pc + L * 8, (L == 2) ? 1 : 0);
    lin_in = nodeB;
  }
  k_mlp<<<NG, 256, 0, stream>>>((const float*)pooled, Wlin, blin, Wout, bout, out);
}

// Round 7
// 483.262 us; speedup vs baseline: 9.0579x; 9.0579x over previous
//
#include <hip/hip_runtime.h>
#include <hip/hip_fp16.h>
#include <math.h>

#define N_NODES 50000
#define E_EDGES 800000
#define E_TOT   850000   // E + N self loops
#define HC 128
#define NHEAD 4
#define LIN 256
#define OUTC 10
#define NG 64
#define NEG_SLOPE 0.2f

// (dst, src-tile)-sorted CSR (R16): edges of each node contiguous,
// tile-ordered; V_old aggr consumes [offT[n*NT], offT[(n+1)*NT]) unchanged.
#define NT 5
#define TILE_N 10000
#define NSEG (N_NODES * NT)     // 250000 (dst,tile) cells
#define SCAN_BLOCKS 245         // 245 * 1024 cells >= NSEG

__device__ __forceinline__ float lrelu(float v) { return v > 0.f ? v : NEG_SLOPE * v; }

typedef _Float16 half8v __attribute__((ext_vector_type(8)));
typedef float    float4v __attribute__((ext_vector_type(4)));

// ---------------------------------------------------------------------------
// MFMA GEMM + attention logits.
// R18 change: A-operand LDS staging. The old per-lane A-frag load read 16
// different rows x 32B per instr (16 scattered spans -> random-gather regime,
// ~4x slower than streams per R2/R3 MSHR evidence). Now the 64x128 x-tile is
// staged into LDS with fully coalesced float4 loads (consecutive lanes ->
// consecutive 16B), converted fp32->fp16 once, and A-frags come from
// ds_read_b128 at the same proven stride-136 padding as the B-frags.
// xt shares LDS with hst (xt dead after the MFMA loop; hst epilogue-only);
// both are 64x136 halves, per-wave 16-row slices line up exactly.
// Fragment layouts (verified m89/m120):
//   A: lane(m=lane&15, quad=lane>>4) holds A[m][quad*8+j], j=0..7
//   B: lane(n=lane&15, quad)        holds B[quad*8+j][n]
//   C/D: col=lane&15, row=quad*4+reg
// ---------------------------------------------------------------------------
__global__ __launch_bounds__(256) void k_gemm_mfma(
    const float* __restrict__ x, const float* __restrict__ W,
    const float* __restrict__ a_s, const float* __restrict__ a_d,
    __half* __restrict__ h, float* __restrict__ asrc, float* __restrict__ adst) {
  __shared__ _Float16 Wt[128 * 136];       // W^T fp16, padded row stride 136
  __shared__ _Float16 xt[64 * 136];        // x-tile fp16 (later reused as hst)
  __shared__ float aS[HC], aD[HC];
  _Float16 (*hst)[16][136] = (_Float16 (*)[16][136])xt;  // epilogue alias
  int tid = threadIdx.x;
  if (tid < HC) { aS[tid] = a_s[tid]; aD[tid] = a_d[tid]; }
  // transpose + convert W (coalesced global read, scattered one-time LDS write)
  for (int i = 0; i < 64; i++) {
    int idx = tid + i * 256;               // 16384 elements
    int k = idx >> 7, n = idx & 127;
    Wt[n * 136 + k] = (_Float16)W[idx];
  }
  // stage x-tile: 64 rows x 128 f32 = 2048 float4s, 8 per thread, coalesced
  {
    int rowbase0 = blockIdx.x * 64;
#pragma unroll
    for (int i = 0; i < 8; i++) {
      int idx = tid + i * 256;             // f4 index 0..2047
      int row = idx >> 5, c4 = idx & 31;
      int grow = rowbase0 + row;
      if (grow > N_NODES - 1) grow = N_NODES - 1;  // clamp; stores guarded
      float4 f4 = ((const float4*)x)[(size_t)grow * 32 + c4];
      _Float16* p = &xt[row * 136 + c4 * 4];
      p[0] = (_Float16)f4.x; p[1] = (_Float16)f4.y;
      p[2] = (_Float16)f4.z; p[3] = (_Float16)f4.w;
    }
  }
  __syncthreads();

  int wv = tid >> 6, lane = tid & 63;
  int quad = lane >> 4, low = lane & 15;
  int rowbase = blockIdx.x * 64 + wv * 16;

  float4v acc[8];
#pragma unroll
  for (int t = 0; t < 8; t++) acc[t] = (float4v){0.f, 0.f, 0.f, 0.f};

#pragma unroll
  for (int k4 = 0; k4 < 4; k4++) {
    int kb = k4 * 32 + quad * 8;
    half8v af = *(const half8v*)&xt[(wv * 16 + low) * 136 + kb];
    half8v bf[8];
#pragma unroll
    for (int t = 0; t < 8; t++)
      bf[t] = *(const half8v*)&Wt[(t * 16 + low) * 136 + kb];
#pragma unroll
    for (int t = 0; t < 8; t++)
      acc[t] = __builtin_amdgcn_mfma_f32_16x16x32_f16(af, bf[t], acc[t], 0, 0, 0);
  }
  __syncthreads();   // all xt reads done before reuse as hst

  // stage C (fp16) into LDS: lane writes rows quad*4+r, feature t*16+low
#pragma unroll
  for (int t = 0; t < 8; t++)
#pragma unroll
    for (int r = 0; r < 4; r++)
      hst[wv][quad * 4 + r][t * 16 + low] = (_Float16)acc[t][r];
  __syncthreads();

  // coalesced h store: lane -> row lane/4, 64B quarter lane%4
  {
    int r = lane >> 2, part = lane & 3;
    int grow = rowbase + r;
    if (grow < N_NODES) {
      const float4* src = (const float4*)&hst[wv][r][part * 32];
      float4* dst = (float4*)(h + (size_t)grow * HC + part * 32);
#pragma unroll
      for (int i = 0; i < 4; i++) dst[i] = src[i];
    }
  }
  // alpha: lane (row=low, head=quad) dots 32 staged feats with a_s / a_d
  {
    int grow = rowbase + low;
    float ss = 0.f, dd = 0.f;
#pragma unroll
    for (int i = 0; i < 32; i++) {
      float hv = (float)hst[wv][low][quad * 32 + i];
      ss += hv * aS[quad * 32 + i];
      dd += hv * aD[quad * 32 + i];
    }
    if (grow < N_NODES) {
      asrc[grow * NHEAD + quad] = ss;
      adst[grow * NHEAD + quad] = dd;
    }
  }
}

// ---------------------------------------------------------------------------
// CSR build, counting-sorted by (dst, src_tile). Hierarchical scan (R16).
// ---------------------------------------------------------------------------
__global__ __launch_bounds__(256) void k_hist(
    const int* __restrict__ dst, const int* __restrict__ src,
    int* __restrict__ degT) {
  int e = blockIdx.x * 256 + threadIdx.x;
  if (e >= E_TOT) return;
  int d, s;
  if (e < E_EDGES) { d = dst[e]; s = src[e]; } else { d = s = e - E_EDGES; }
  int t = s / TILE_N;
  atomicAdd(&degT[d * NT + t], 1);
}

__global__ __launch_bounds__(256) void k_scanA(
    const int* __restrict__ degT, int* __restrict__ bsum) {
  __shared__ int ps[256];
  int tid = threadIdx.x, b = blockIdx.x;
  int base = b * 1024 + tid * 4;
  int s = 0;
#pragma unroll
  for (int i = 0; i < 4; i++) {
    int idx = base + i;
    if (idx < NSEG) s += degT[idx];
  }
  ps[tid] = s;
  __syncthreads();
  for (int off = 128; off > 0; off >>= 1) {
    if (tid < off) ps[tid] += ps[tid + off];
    __syncthreads();
  }
  if (tid == 0) bsum[b] = ps[0];
}

// scanB: exclusive scan of the 245 block sums (+ pooled zeroing folded in)
__global__ __launch_bounds__(256) void k_scanB(
    const int* __restrict__ bsum, int* __restrict__ boff,
    unsigned* __restrict__ pooled) {
  __shared__ int ps[256];
  int tid = threadIdx.x;
  {
    uint4* p4 = (uint4*)pooled;
#pragma unroll
    for (int i = 0; i < 8; i++) p4[tid * 8 + i] = make_uint4(0u, 0u, 0u, 0u);
  }
  int s = (tid < SCAN_BLOCKS) ? bsum[tid] : 0;
  ps[tid] = s;
  __syncthreads();
  for (int off = 1; off < 256; off <<= 1) {
    int v = (tid >= off) ? ps[tid - off] : 0;
    __syncthreads();
    ps[tid] += v;
    __syncthreads();
  }
  if (tid < SCAN_BLOCKS) boff[tid] = ps[tid] - s;  // exclusive
}

__global__ __launch_bounds__(256) void k_scanC(
    const int* __restrict__ degT, const int* __restrict__ boff,
    int* __restrict__ offT) {
  __shared__ int ps[256];
  int tid = threadIdx.x, b = blockIdx.x;
  int base = b * 1024 + tid * 4;
  int d[4];
  int s = 0;
#pragma unroll
  for (int i = 0; i < 4; i++) {
    int idx = base + i;
    d[i] = (idx < NSEG) ? degT[idx] : 0;
    s += d[i];
  }
  ps[tid] = s;
  __syncthreads();
  for (int off = 1; off < 256; off <<= 1) {
    int v = (tid >= off) ? ps[tid - off] : 0;
    __syncthreads();
    ps[tid] += v;
    __syncthreads();
  }
  int run = boff[b] + ps[tid] - s;
#pragma unroll
  for (int i = 0; i < 4; i++) {
    int idx = base + i;
    if (idx < NSEG) {
      offT[idx] = run;
      run += d[i];
      if (idx == NSEG - 1) offT[NSEG] = run;
    }
  }
}

__global__ __launch_bounds__(256) void k_scatter(
    const int* __restrict__ src, const int* __restrict__ dst,
    const int* __restrict__ offT, int* __restrict__ cntT,
    int* __restrict__ csr_src) {
  int e = blockIdx.x * 256 + threadIdx.x;
  if (e >= E_TOT) return;
  int s, d;
  if (e < E_EDGES) { s = src[e]; d = dst[e]; } else { s = d = e - E_EDGES; }
  int t = s / TILE_N;
  int pos = offT[d * NT + t] + atomicAdd(&cntT[d * NT + t], 1);
  csr_src[pos] = s;
}

#define BFLY_MAX4(m0, m1, m2, m3)                         \
  _Pragma("unroll") for (int off = 1; off < 64; off <<= 1) { \
    m0 = fmaxf(m0, __shfl_xor(m0, off));                  \
    m1 = fmaxf(m1, __shfl_xor(m1, off));                  \
    m2 = fmaxf(m2, __shfl_xor(m2, off));                  \
    m3 = fmaxf(m3, __shfl_xor(m3, off));                  \
  }
#define BFLY_SUM4(s0, s1, s2, s3)                         \
  _Pragma("unroll") for (int off = 1; off < 64; off <<= 1) { \
    s0 += __shfl_xor(s0, off);                            \
    s1 += __shfl_xor(s1, off);                            \
    s2 += __shfl_xor(s2, off);                            \
    s3 += __shfl_xor(s3, off);                            \
  }

// ---------------------------------------------------------------------------
// Fused softmax + aggregation — V_old structure, verbatim (proven; R5=508us
// total with tiled CSR). One wave per dst node; lane owns 2 feats;
// head = lane/16. LAW (R5/R7/R10, re-confirmed R13): every gather
// instruction's 64 lanes cover exactly ONE contiguous h-row span.
// History: R12/R13 quad-row gather = 190us; R14 async LDS staging = 200us;
// R15 per-edge recompute = ~280us; R17 persistent+soft-barriers = 1448us
// (aligned tiles DID cut FETCH 99->56GB, but 2-deep chain killed MLP).
// Keep the 8-deep LDS-precomputed-weight gather; it is the structure.
// ---------------------------------------------------------------------------
__global__ __launch_bounds__(256) void k_aggr(
    const int* __restrict__ offT, const int* __restrict__ csr_src,
    const float* __restrict__ asrc, const float* __restrict__ adst,
    const __half* __restrict__ h, const float* __restrict__ bias,
    const int* __restrict__ batch, float* __restrict__ out_h,
    unsigned* __restrict__ pooled, int do_pool) {
  __shared__ int   sv_lds[4][64];
  __shared__ float w_lds[4][64][4];
  int gid = blockIdx.x * 256 + threadIdx.x;
  int node = gid >> 6, lane = gid & 63, wl = threadIdx.x >> 6;
  if (node >= N_NODES) return;
  int head = lane >> 4;
  int lo = offT[node * NT], hi = offT[node * NT + NT];
  int deg = hi - lo;
  float4 ad4 = ((const float4*)adst)[node];  // broadcast
  float ax = 0.f, ay = 0.f;
  float S;

  if (deg <= 64) {
    int j = lo + lane;
    int sv = (j < hi) ? csr_src[j] : 0;
    float4 a4 = ((const float4*)asrc)[sv];
    bool valid = (j < hi);
    float e0 = valid ? lrelu(a4.x + ad4.x) : -1e30f;
    float e1 = valid ? lrelu(a4.y + ad4.y) : -1e30f;
    float e2 = valid ? lrelu(a4.z + ad4.z) : -1e30f;
    float e3 = valid ? lrelu(a4.w + ad4.w) : -1e30f;
    float m0 = e0, m1 = e1, m2 = e2, m3 = e3;
    BFLY_MAX4(m0, m1, m2, m3)
    float w0 = expf(e0 - m0), w1 = expf(e1 - m1);
    float w2 = expf(e2 - m2), w3 = expf(e3 - m3);  // invalid lanes -> 0
    float s0 = w0, s1 = w1, s2 = w2, s3 = w3;
    BFLY_SUM4(s0, s1, s2, s3)
    sv_lds[wl][lane] = sv;
    *(float4*)&w_lds[wl][lane][0] = make_float4(w0, w1, w2, w3);
    S = (head == 0) ? s0 : (head == 1) ? s1 : (head == 2) ? s2 : s3;
    int jj = 0;
    for (; jj + 8 <= deg; jj += 8) {
      int i0 = sv_lds[wl][jj + 0], i1 = sv_lds[wl][jj + 1];
      int i2 = sv_lds[wl][jj + 2], i3 = sv_lds[wl][jj + 3];
      int i4 = sv_lds[wl][jj + 4], i5 = sv_lds[wl][jj + 5];
      int i6 = sv_lds[wl][jj + 6], i7 = sv_lds[wl][jj + 7];
      float wA = w_lds[wl][jj + 0][head], wB = w_lds[wl][jj + 1][head];
      float wC = w_lds[wl][jj + 2][head], wD = w_lds[wl][jj + 3][head];
      float wE = w_lds[wl][jj + 4][head], wF = w_lds[wl][jj + 5][head];
      float wG = w_lds[wl][jj + 6][head], wH = w_lds[wl][jj + 7][head];
      float2 h0 = __half22float2(*(const __half2*)(h + (size_t)i0 * HC + lane * 2));
      float2 h1 = __half22float2(*(const __half2*)(h + (size_t)i1 * HC + lane * 2));
      float2 h2 = __half22float2(*(const __half2*)(h + (size_t)i2 * HC + lane * 2));
      float2 h3 = __half22float2(*(const __half2*)(h + (size_t)i3 * HC + lane * 2));
      float2 h4 = __half22float2(*(const __half2*)(h + (size_t)i4 * HC + lane * 2));
      float2 h5 = __half22float2(*(const __half2*)(h + (size_t)i5 * HC + lane * 2));
      float2 h6 = __half22float2(*(const __half2*)(h + (size_t)i6 * HC + lane * 2));
      float2 h7 = __half22float2(*(const __half2*)(h + (size_t)i7 * HC + lane * 2));
      ax += wA * h0.x; ay += wA * h0.y;
      ax += wB * h1.x; ay += wB * h1.y;
      ax += wC * h2.x; ay += wC * h2.y;
      ax += wD * h3.x; ay += wD * h3.y;
      ax += wE * h4.x; ay += wE * h4.y;
      ax += wF * h5.x; ay += wF * h5.y;
      ax += wG * h6.x; ay += wG * h6.y;
      ax += wH * h7.x; ay += wH * h7.y;
    }
    for (; jj + 4 <= deg; jj += 4) {
      int i0 = sv_lds[wl][jj + 0], i1 = sv_lds[wl][jj + 1];
      int i2 = sv_lds[wl][jj + 2], i3 = sv_lds[wl][jj + 3];
      float wA = w_lds[wl][jj + 0][head], wB = w_lds[wl][jj + 1][head];
      float wC = w_lds[wl][jj + 2][head], wD = w_lds[wl][jj + 3][head];
      float2 h0 = __half22float2(*(const __half2*)(h + (size_t)i0 * HC + lane * 2));
      float2 h1 = __half22float2(*(const __half2*)(h + (size_t)i1 * HC + lane * 2));
      float2 h2 = __half22float2(*(const __half2*)(h + (size_t)i2 * HC + lane * 2));
      float2 h3 = __half22float2(*(const __half2*)(h + (size_t)i3 * HC + lane * 2));
      ax += wA * h0.x; ay += wA * h0.y;
      ax += wB * h1.x; ay += wB * h1.y;
      ax += wC * h2.x; ay += wC * h2.y;
      ax += wD * h3.x; ay += wD * h3.y;
    }
    for (; jj < deg; jj++) {
      int i0 = sv_lds[wl][jj];
      float wA = w_lds[wl][jj][head];
      float2 h0 = __half22float2(*(const __half2*)(h + (size_t)i0 * HC + lane * 2));
      ax += wA * h0.x; ay += wA * h0.y;
    }
  } else {
    // rare generic path (deg > 64): chunked two-pass
    float M0 = -1e30f, M1 = -1e30f, M2 = -1e30f, M3 = -1e30f;
    for (int c = lo; c < hi; c += 64) {
      int j = c + lane;
      int sv = (j < hi) ? csr_src[j] : 0;
      float4 a4 = ((const float4*)asrc)[sv];
      bool valid = (j < hi);
      float e0 = valid ? lrelu(a4.x + ad4.x) : -1e30f;
      float e1 = valid ? lrelu(a4.y + ad4.y) : -1e30f;
      float e2 = valid ? lrelu(a4.z + ad4.z) : -1e30f;
      float e3 = valid ? lrelu(a4.w + ad4.w) : -1e30f;
      BFLY_MAX4(e0, e1, e2, e3)
      M0 = fmaxf(M0, e0); M1 = fmaxf(M1, e1);
      M2 = fmaxf(M2, e2); M3 = fmaxf(M3, e3);
    }
    float S0 = 0.f, S1 = 0.f, S2 = 0.f, S3 = 0.f;
    for (int c = lo; c < hi; c += 64) {
      int j = c + lane;
      int sv = (j < hi) ? csr_src[j] : 0;
      float4 a4 = ((const float4*)asrc)[sv];
      bool valid = (j < hi);
      float e0 = valid ? lrelu(a4.x + ad4.x) : -1e30f;
      float e1 = valid ? lrelu(a4.y + ad4.y) : -1e30f;
      float e2 = valid ? lrelu(a4.z + ad4.z) : -1e30f;
      float e3 = valid ? lrelu(a4.w + ad4.w) : -1e30f;
      float w0 = expf(e0 - M0), w1 = expf(e1 - M1);
      float w2 = expf(e2 - M2), w3 = expf(e3 - M3);
      float s0 = w0, s1 = w1, s2 = w2, s3 = w3;
      BFLY_SUM4(s0, s1, s2, s3)
      S0 += s0; S1 += s1; S2 += s2; S3 += s3;
      sv_lds[wl][lane] = sv;
      *(float4*)&w_lds[wl][lane][0] = make_float4(w0, w1, w2, w3);
      int cnt = (hi - c < 64) ? (hi - c) : 64;
      int jj = 0;
      for (; jj + 4 <= cnt; jj += 4) {
        int i0 = sv_lds[wl][jj + 0], i1 = sv_lds[wl][jj + 1];
        int i2 = sv_lds[wl][jj + 2], i3 = sv_lds[wl][jj + 3];
        float wA = w_lds[wl][jj + 0][head], wB = w_lds[wl][jj + 1][head];
        float wC = w_lds[wl][jj + 2][head], wD = w_lds[wl][jj + 3][head];
        float2 h0 = __half22float2(*(const __half2*)(h + (size_t)i0 * HC + lane * 2));
        float2 h1 = __half22float2(*(const __half2*)(h + (size_t)i1 * HC + lane * 2));
        float2 h2 = __half22float2(*(const __half2*)(h + (size_t)i2 * HC + lane * 2));
        float2 h3 = __half22float2(*(const __half2*)(h + (size_t)i3 * HC + lane * 2));
        ax += wA * h0.x; ay += wA * h0.y;
        ax += wB * h1.x; ay += wB * h1.y;
        ax += wC * h2.x; ay += wC * h2.y;
        ax += wD * h3.x; ay += wD * h3.y;
      }
      for (; jj < cnt; jj++) {
        int i0 = sv_lds[wl][jj];
        float wA = w_lds[wl][jj][head];
        float2 h0 = __half22float2(*(const __half2*)(h + (size_t)i0 * HC + lane * 2));
        ax += wA * h0.x; ay += wA * h0.y;
      }
    }
    S = (head == 0) ? S0 : (head == 1) ? S1 : (head == 2) ? S2 : S3;
  }

  float rden = 1.f / S;
  float2 b = *(const float2*)(bias + lane * 2);
  float vx = fmaxf(ax * rden + b.x, 0.f);
  float vy = fmaxf(ay * rden + b.y, 0.f);
  *(float2*)(out_h + (size_t)node * HC + lane * 2) = make_float2(vx, vy);
  if (do_pool) {
    int g = batch[node];
    unsigned* pp = pooled + g * HC + lane * 2;
    // post-relu values >= 0: bit compare == float compare; init 0 matches the
    // reference's where(isfinite, pooled, 0) empty-graph guard.
    atomicMax(pp + 0, __float_as_uint(vx));
    atomicMax(pp + 1, __float_as_uint(vy));
  }
}

// final head: out[g] = (pooled[g] @ Wlin + blin) @ Wout + bout ; 1 block/graph
__global__ __launch_bounds__(256) void k_mlp(
    const float* __restrict__ pooled, const float* __restrict__ Wlin,
    const float* __restrict__ blin, const float* __restrict__ Wout,
    const float* __restrict__ bout, float* __restrict__ out) {
  __shared__ float p[HC];
  __shared__ float z[LIN];
  int g = blockIdx.x, tid = threadIdx.x;
  if (tid < HC) p[tid] = pooled[g * HC + tid];
  __syncthreads();
  float zv = blin[tid];
  for (int k = 0; k < HC; k++) zv += p[k] * Wlin[k * LIN + tid];
  z[tid] = zv;
  __syncthreads();
  if (tid < OUTC) {
    float o = bout[tid];
    for (int k = 0; k < LIN; k++) o += z[k] * Wout[k * OUTC + tid];
    out[g * OUTC + tid] = o;
  }
}

extern "C" void kernel_launch(void* const* d_in, const int* in_sizes, int n_in,
                              void* d_out, int out_size, void* d_ws, size_t ws_size,
                              hipStream_t stream) {
  const float* x     = (const float*)d_in[0];
  const int*   ei    = (const int*)d_in[1];
  const int*   batch = (const int*)d_in[2];
  const float* Wl[3] = {(const float*)d_in[3], (const float*)d_in[7], (const float*)d_in[11]};
  const float* As[3] = {(const float*)d_in[4], (const float*)d_in[8], (const float*)d_in[12]};
  const float* Ad[3] = {(const float*)d_in[5], (const float*)d_in[9], (const float*)d_in[13]};
  const float* Bi[3] = {(const float*)d_in[6], (const float*)d_in[10], (const float*)d_in[14]};
  const float* Wlin  = (const float*)d_in[15];
  const float* blin  = (const float*)d_in[16];
  const float* Wout  = (const float*)d_in[17];
  const float* bout  = (const float*)d_in[18];
  float* out = (float*)d_out;

  // workspace layout (float offsets)
  float* ws = (float*)d_ws;
  __half*   h       = (__half*)ws;                 // N*128 halves (3.2M fl)
  float*    nodeB   = ws + 3200000;                // N*128 fp32   (6.4M fl)
  float*    asrc    = ws + 9600000;                // N*4
  float*    adst    = ws + 9800000;                // N*4
  int*      degT    = (int*)(ws + 10000000);       // 250k (adjacent to cntT)
  int*      cntT    = (int*)(ws + 10250000);       // 250k
  int*      offT    = (int*)(ws + 10500000);       // 250001
  int*      csr_src = (int*)(ws + 10750004);       // E_TOT (+pad)
  unsigned* pooled  = (unsigned*)(ws + 11600008);  // 64*128
  int*      bsum    = (int*)(ws + 11608200);       // 245
  int*      boff    = (int*)(ws + 11608456);       // 245

  const int* srcp = ei;
  const int* dstp = ei + E_EDGES;

  hipMemsetAsync(degT, 0, 2 * NSEG * sizeof(int), stream);  // degT + cntT

  // (dst, src_tile)-sorted CSR — built once, reused by all 3 layers
  k_hist<<<(E_TOT + 255) / 256, 256, 0, stream>>>(dstp, srcp, degT);
  k_scanA<<<SCAN_BLOCKS, 256, 0, stream>>>(degT, bsum);
  k_scanB<<<1, 256, 0, stream>>>(bsum, boff, pooled);
  k_scanC<<<SCAN_BLOCKS, 256, 0, stream>>>(degT, boff, offT);
  k_scatter<<<(E_TOT + 255) / 256, 256, 0, stream>>>(srcp, dstp, offT, cntT, csr_src);

  const float* lin_in = x;
  for (int L = 0; L < 3; L++) {
    k_gemm_mfma<<<(N_NODES + 63) / 64, 256, 0, stream>>>(
        lin_in, Wl[L], As[L], Ad[L], h, asrc, adst);
    k_aggr<<<(N_NODES * 64 + 255) / 256, 256, 0, stream>>>(
        offT, csr_src, asrc, adst, h, Bi[L], batch,
        nodeB, pooled, (L == 2) ? 1 : 0);
    lin_in = nodeB;
  }
  k_mlp<<<NG, 256, 0, stream>>>((const float*)pooled, Wlin, blin, Wout, bout, out);
}